// Round 15
// baseline (2072.213 us; speedup 1.0000x reference)
//
#include <hip/hip_runtime.h>
#include <cstdio>

#ifndef __has_builtin
#define __has_builtin(x) 0
#endif

// ---------------- problem constants ----------------
#define NB      256
#define NT      48
#define NS      512
#define KAHEAD  4
#define NTHREADS 1024
#define NBLOCKS  256
#define GSIZE    32
#define RSTRIDE  544     // exchange row floats (512 d / 513 x used)
#define XSLOT    512     // x scalar slot
#define XROWB    1104    // LDS f16 panel row stride bytes (69 quads: conflict-free)

// ---------------- workspace (float offsets) ----------------
#define WS_D     0              // [256][544] d exchange fp32
#define WS_X     139264         // [256][544] x exchange
#define WS_WHB   278528         // f16 [16 nt][32 kt][64 l][8] Wh B-frags (512KB, ex-lh slot)
#define WS_BAR   409600         // 256 uints
#define WS_WA    409856         // f16 [32 cix][2 nt][32 kt][512]
#define WS_WC    934144         // f16 [32 cix][32 kt][512]
#define WS_WN    1196288        // f16 [32 cix][16 kt][512]
#define WS_WS    1327360        // f16 [32 nt][16 kt][512]
#define WS_FLOATS 1458432       // 5.83 MB

// ---------------- LDS (byte offsets), total 156432 ----------------
#define L_XHI    0              // f16 panel hi [32][1104B] 35328
#define L_XLO    35328
#define L_LSB    70656          // ushort [48][512] f16 ls 49152
#define L_GH     119808         // float [3][32][17]
#define L_GI     126336
#define L_LH     132864         // float [512]
#define L_WO     134912
#define L_E      136960
#define L_ATT    137216
#define L_H1P    139520
#define L_H1S    143616
#define L_H2P    144640
#define L_H2S    146688
#define L_H3P    147200
#define L_MISC   148224
#define L_PB     148240         // float[2048] K-split partial buffer (8KB)
#define LDS_BYTES 156432

typedef float    f4v  __attribute__((ext_vector_type(4)));
typedef float    f16v __attribute__((ext_vector_type(16)));
typedef _Float16 h4v  __attribute__((ext_vector_type(4)));
typedef _Float16 h8v  __attribute__((ext_vector_type(8)));

// ---------------- MFMA (f16) ----------------
__device__ __forceinline__ f16v MFMA32(h8v a, h8v b, f16v c) {
    return __builtin_amdgcn_mfma_f32_32x32x16_f16(a, b, c, 0, 0, 0);
}
__device__ __forceinline__ f4v MFMA16(h8v a, h8v b, f4v c) {
    return __builtin_amdgcn_mfma_f32_16x16x32_f16(a, b, c, 0, 0, 0);
}

#if __has_builtin(__builtin_bit_cast)
#define F2H_BITS(v) __builtin_bit_cast(h8v, (v))
#define H2F_BITS(v) __builtin_bit_cast(f4v, (v))
#else
__device__ __forceinline__ h8v f2h_bits_(f4v v) { union { f4v f; h8v h; } u; u.f = v; return u.h; }
__device__ __forceinline__ f4v h2f_bits_(h8v v) { union { f4v f; h8v h; } u; u.h = v; return u.f; }
#define F2H_BITS(v) f2h_bits_(v)
#define H2F_BITS(v) h2f_bits_(v)
#endif

// ---------------- math ----------------
__device__ __forceinline__ float frcp_(float x) {
#if __has_builtin(__builtin_amdgcn_rcpf)
    return __builtin_amdgcn_rcpf(x);
#else
    return 1.0f / x;
#endif
}
__device__ __forceinline__ float ftanh_(float x) {
    float e = __expf(2.0f * x);
    return 1.0f - 2.0f * frcp_(e + 1.0f);
}
__device__ __forceinline__ float fsig_(float x) { return frcp_(1.0f + __expf(-x)); }
__device__ __forceinline__ float lrelu_(float x) { return fmaxf(x, 0.01f * x); }
__device__ __forceinline__ void split16_(float v, _Float16& hi, _Float16& lo) {
    _Float16 h = (_Float16)v;
    hi = h;
    lo = (_Float16)(v - (float)h);
}
__device__ __forceinline__ unsigned short f2hbits_(float v) {
    union { _Float16 h; unsigned short u; } c; c.h = (_Float16)v; return c.u;
}
__device__ __forceinline__ float hbits2f_(unsigned short u) {
    union { unsigned short u; _Float16 h; } c; c.u = u; return (float)c.h;
}

// ---------------- XCD-local (L2) coherent access: sc0 = L1-bypass ----------------
__device__ __forceinline__ void cstore1(float* p, float v) {
    asm volatile("global_store_dword %0, %1, off sc0" :: "v"(p), "v"(v) : "memory");
}
__device__ __forceinline__ f4v cload4(const float* p) {
    f4v v;
    asm volatile("global_load_dwordx4 %0, %1, off sc0" : "=v"(v) : "v"(p));
    return v;
}
__device__ __forceinline__ float cload1(const float* p) {
    float v;
    asm volatile("global_load_dword %0, %1, off sc0" : "=v"(v) : "v"(p));
    return v;
}
__device__ __forceinline__ void cwait() {
    asm volatile("s_waitcnt vmcnt(0)" ::: "memory");
    __builtin_amdgcn_sched_barrier(0);
}

// Group barrier: proven __hip_atomic AGENT-scope pair (r5-r8, r12, r14 at floor).
__device__ __forceinline__ void gbar(unsigned* bar, unsigned* epoch) {
    asm volatile("s_waitcnt vmcnt(0)" ::: "memory");
    __syncthreads();
    if (threadIdx.x == 0) {
        *epoch += GSIZE;
        __hip_atomic_fetch_add(bar, 1u, __ATOMIC_RELAXED, __HIP_MEMORY_SCOPE_AGENT);
        unsigned target = *epoch;
        int guard = 0;
        while (__hip_atomic_load(bar, __ATOMIC_RELAXED, __HIP_MEMORY_SCOPE_AGENT) < target) {
#if __has_builtin(__builtin_amdgcn_s_sleep)
            __builtin_amdgcn_s_sleep(1);
#endif
            if (++guard > (1 << 17)) break;
        }
    }
    __syncthreads();
}

// ---------------- staging: fp32 exchange panel -> LDS f16 hi/lo ----------------
__device__ __forceinline__ void cvtStore_(char* hiB, char* loB, int idx, f4v v) {
    unsigned row = (unsigned)idx / 544u;
    unsigned col = (unsigned)idx - row * 544u;
    h4v h, l;
    #pragma unroll
    for (int i = 0; i < 4; ++i) { _Float16 hh, ll; split16_(v[i], hh, ll); h[i] = hh; l[i] = ll; }
    *(h4v*)(hiB + row * XROWB + col * 2) = h;
    *(h4v*)(loB + row * XROWB + col * 2) = l;
}
__device__ __forceinline__ void stagePanel(const float* __restrict__ gsrc,
                                           char* __restrict__ hiB,
                                           char* __restrict__ loB, int tid) {
    f4v v0 = cload4(gsrc + tid * 4);
    f4v v1 = cload4(gsrc + 4096 + tid * 4);
    f4v v2 = cload4(gsrc + 8192 + tid * 4);
    f4v v3 = cload4(gsrc + 12288 + tid * 4);
    f4v v4 = {0.f, 0.f, 0.f, 0.f};
    if (tid < 256) v4 = cload4(gsrc + 16384 + tid * 4);
    cwait();
    cvtStore_(hiB, loB, tid * 4, v0);
    cvtStore_(hiB, loB, 4096 + tid * 4, v1);
    cvtStore_(hiB, loB, 8192 + tid * 4, v2);
    cvtStore_(hiB, loB, 12288 + tid * 4, v3);
    if (tid < 256) cvtStore_(hiB, loB, 16384 + tid * 4, v4);
}

// ---------------- GEMMs with register-resident B (macros: guaranteed inline) ----------------
// Merged A: waves 0-3 gh MFMA (reg weights); waves 4-11 lh_own via
// REPLICATED-ROW MFMA (A = broadcast own d row from LDS, B = whB streamed
// from L2). lh numerics = r13-proven (single-f16 d x f16 Wh, floor-accurate).
// lh_s is written BEFORE the internal sync -> attention can follow barrier-free.
#define DO_GEMMA(doLH) do {                                                          \
    f16v acc_ = (f16v){0,0,0,0,0,0,0,0,0,0,0,0,0,0,0,0};                             \
    if (w < 4) {                                                                     \
        const int kc_ = w >> 1;                                                      \
        const int aoff_ = (l & 31) * XROWB + ((l >> 5) << 4);                        \
        _Pragma("unroll")                                                            \
        for (int kt = 0; kt < 16; ++kt) {                                            \
            h8v ah = *(const h8v*)(smem + L_XHI + aoff_ + (kc_ * 16 + kt) * 32);     \
            h8v al = *(const h8v*)(smem + L_XLO + aoff_ + (kc_ * 16 + kt) * 32);     \
            acc_ = MFMA32(ah, wreg[kt], acc_);                                       \
            acc_ = MFMA32(al, wreg[kt], acc_);                                       \
        }                                                                            \
        if (kc_ == 1) {                                                              \
            _Pragma("unroll")                                                        \
            for (int r = 0; r < 16; ++r) pbuf[(w & 1) * 1024 + r * 64 + l] = acc_[r];\
        }                                                                            \
    } else if (doLH && w < 12) {                                                     \
        const int base_ = cix * XROWB + ((l >> 5) << 4);                             \
        _Pragma("unroll")                                                            \
        for (int sub_ = 0; sub_ < 2; ++sub_) {                                       \
            const int nt_ = (w - 4) * 2 + sub_;                                      \
            const _Float16* bp_ = whB + ((long)(nt_ * 32) << 9) + (l << 3);          \
            f16v la_ = (f16v){0,0,0,0,0,0,0,0,0,0,0,0,0,0,0,0};                      \
            _Pragma("unroll 8")                                                      \
            for (int kt = 0; kt < 32; ++kt) {                                        \
                h8v ah = *(const h8v*)(smem + L_XHI + base_ + kt * 32);              \
                h8v bb = *(const h8v*)(bp_ + (kt << 9));                             \
                la_ = MFMA32(ah, bb, la_);                                           \
            }                                                                        \
            if (l < 32) lh_s[nt_ * 32 + l] = la_[0] + bh[nt_ * 32 + l];              \
        }                                                                            \
    }                                                                                \
    __syncthreads();                                                                 \
    if (w < 2) {                                                                     \
        _Pragma("unroll")                                                            \
        for (int r = 0; r < 16; ++r) acc_[r] += pbuf[w * 1024 + r * 64 + l];         \
        const int c_ = w * 32 + (l & 31);                                            \
        const int rb_ = (l >> 5) << 2;                                               \
        if (c_ >= 16) {                                                              \
            const int gate_ = (c_ - 16) >> 4, jj_ = (c_ - 16) & 15;                  \
            const float bb_ = b_hh[gate_ * 512 + cix * 16 + jj_];                    \
            _Pragma("unroll")                                                        \
            for (int r = 0; r < 16; ++r) {                                           \
                int row_ = (r & 3) + ((r >> 2) << 3) + rb_;                          \
                ghs[gate_ * 544 + row_ * 17 + jj_] = acc_[r] + bb_;                  \
            }                                                                        \
        }                                                                            \
    }                                                                                \
} while (0)

// waves 4-5: rz (kc=w-4); waves 6-7: n (kc=w-6); internal __syncthreads for all
#define DO_GEMMC() do {                                                              \
    f16v acc_ = (f16v){0,0,0,0,0,0,0,0,0,0,0,0,0,0,0,0};                             \
    f4v an0_ = {0.f,0.f,0.f,0.f}, an1_ = {0.f,0.f,0.f,0.f};                          \
    if (w == 4 || w == 5) {                                                          \
        const int kc_ = w - 4;                                                       \
        const int aoff_ = (l & 31) * XROWB + ((l >> 5) << 4);                        \
        _Pragma("unroll")                                                            \
        for (int kt = 0; kt < 16; ++kt) {                                            \
            h8v ah = *(const h8v*)(smem + L_XHI + aoff_ + (kc_ * 16 + kt) * 32);     \
            h8v al = *(const h8v*)(smem + L_XLO + aoff_ + (kc_ * 16 + kt) * 32);     \
            acc_ = MFMA32(ah, wreg[kt], acc_);                                       \
            acc_ = MFMA32(al, wreg[kt], acc_);                                       \
        }                                                                            \
        if (kc_ == 1) {                                                              \
            _Pragma("unroll")                                                        \
            for (int r = 0; r < 16; ++r) pbuf[r * 64 + l] = acc_[r];                 \
        }                                                                            \
    } else if (w == 6 || w == 7) {                                                   \
        const int kc_ = w - 6;                                                       \
        const int a0_ = (l & 15) * XROWB + ((l >> 4) << 4);                          \
        const int a1_ = a0_ + 16 * XROWB;                                            \
        _Pragma("unroll")                                                            \
        for (int kt = 0; kt < 8; ++kt) {                                             \
            const int kb_ = (kc_ * 8 + kt) * 64;                                     \
            h8v ah0 = *(const h8v*)(smem + L_XHI + a0_ + kb_);                       \
            h8v al0 = *(const h8v*)(smem + L_XLO + a0_ + kb_);                       \
            h8v ah1 = *(const h8v*)(smem + L_XHI + a1_ + kb_);                       \
            h8v al1 = *(const h8v*)(smem + L_XLO + a1_ + kb_);                       \
            an0_ = MFMA16(ah0, wreg[kt], an0_); an0_ = MFMA16(al0, wreg[kt], an0_);  \
            an1_ = MFMA16(ah1, wreg[kt], an1_); an1_ = MFMA16(al1, wreg[kt], an1_);  \
        }                                                                            \
        if (kc_ == 1) {                                                              \
            _Pragma("unroll")                                                        \
            for (int r = 0; r < 4; ++r) {                                            \
                pbuf[1024 + r * 64 + l] = an0_[r];                                   \
                pbuf[1280 + r * 64 + l] = an1_[r];                                   \
            }                                                                        \
        }                                                                            \
    }                                                                                \
    __syncthreads();                                                                 \
    if (w == 4) {                                                                    \
        _Pragma("unroll")                                                            \
        for (int r = 0; r < 16; ++r) acc_[r] += pbuf[r * 64 + l];                    \
        const int c_ = l & 31, gate_ = c_ >> 4, jj_ = c_ & 15;                       \
        const int rb_ = (l >> 5) << 2;                                               \
        const float bb_ = b_ih[gate_ * 512 + cix * 16 + jj_];                        \
        _Pragma("unroll")                                                            \
        for (int r = 0; r < 16; ++r) {                                               \
            int row_ = (r & 3) + ((r >> 2) << 3) + rb_;                              \
            gis[gate_ * 544 + row_ * 17 + jj_] = acc_[r] + bb_;                      \
        }                                                                            \
    } else if (w == 6) {                                                             \
        const int jj_ = l & 15;                                                      \
        const float bb_ = b_ih[1024 + cix * 16 + jj_];                               \
        _Pragma("unroll")                                                            \
        for (int r = 0; r < 4; ++r) {                                                \
            int row_ = ((l >> 4) << 2) + r;                                          \
            gis[1088 + row_ * 17 + jj_] = an0_[r] + pbuf[1024 + r * 64 + l] + bb_;   \
            gis[1088 + (16 + row_) * 17 + jj_] = an1_[r] + pbuf[1280 + r * 64 + l] + bb_; \
        }                                                                            \
    }                                                                                \
} while (0)

// startup ls GEMM: 16 waves, 16x16x32_f16, K=512; ls stored f16
__device__ __forceinline__ void lsGemm(const char* smem, const _Float16* WS_,
        int tid, int ch, unsigned short* lsb, const float* bs) {
    const int w = tid >> 6, l = tid & 63;
    const int mt = w & 1, ng = w >> 1;
    const int aoff = (mt * 16 + (l & 15)) * XROWB + ((l >> 4) << 4);
    f4v acc[4] = {{0,0,0,0},{0,0,0,0},{0,0,0,0},{0,0,0,0}};
    for (int kt = 0; kt < 16; ++kt) {
        h8v ah = *(const h8v*)(smem + L_XHI + aoff + kt * 64);
        h8v al = *(const h8v*)(smem + L_XLO + aoff + kt * 64);
        #pragma unroll
        for (int i = 0; i < 4; ++i) {
            const _Float16* bp = WS_ + ((long)((ng * 4 + i) * 16 + kt)) * 512 + (l << 3);
            h8v bb = *(const h8v*)bp;
            acc[i] = MFMA16(ah, bb, acc[i]);
            acc[i] = MFMA16(al, bb, acc[i]);
        }
    }
    #pragma unroll
    for (int i = 0; i < 4; ++i) {
        const int n = (ng * 4 + i) * 16 + (l & 15);
        const float bsv = bs[n];
        #pragma unroll
        for (int r = 0; r < 4; ++r) {
            int row = mt * 16 + ((l >> 4) << 2) + r;
            if (row < 24)
                lsb[(ch * 24 + row) * NS + n] = f2hbits_(acc[i][r] + bsv);
        }
    }
}

// ---------------- prep: f16 fragment packing + zeroing ----------------
__global__ void prep_kernel(const float* __restrict__ Whh,
                            const float* __restrict__ Wih,
                            const float* __restrict__ Wh,
                            const float* __restrict__ Ws,
                            float* __restrict__ ws) {
    long i = (long)blockIdx.x * blockDim.x + threadIdx.x;
    long stride = (long)gridDim.x * blockDim.x;
    _Float16* wa  = (_Float16*)(ws + WS_WA);
    _Float16* wc  = (_Float16*)(ws + WS_WC);
    _Float16* wn  = (_Float16*)(ws + WS_WN);
    _Float16* wsls = (_Float16*)(ws + WS_WS);
    _Float16* whb = (_Float16*)(ws + WS_WHB);

    for (long p = i; p < 131072; p += stride) {
        int l = (int)(p & 63);
        long t = p >> 6;
        int kt = (int)(t & 31);
        int u = (int)(t >> 5);
        int nt = u & 1, cix = u >> 1;
        int c = nt * 32 + (l & 31);
        #pragma unroll
        for (int e = 0; e < 8; ++e) {
            int k = kt * 16 + ((l >> 5) << 3) + e;
            float wv;
            if (c < 16) wv = Wh[(long)k * 512 + cix * 16 + c];
            else {
                int gate = (c - 16) >> 4, j = cix * 16 + ((c - 16) & 15);
                wv = Whh[((long)(gate * 512 + j)) * 512 + k];
            }
            wa[p * 8 + e] = (_Float16)wv;
        }
    }
    for (long p = i; p < 65536; p += stride) {
        int l = (int)(p & 63);
        long t = p >> 6;
        int kt = (int)(t & 31), cix = (int)(t >> 5);
        int c = l & 31, gate = c >> 4, j = cix * 16 + (c & 15);
        #pragma unroll
        for (int e = 0; e < 8; ++e) {
            int k = kt * 16 + ((l >> 5) << 3) + e;
            wc[p * 8 + e] = (_Float16)Wih[((long)(gate * 512 + j)) * 513 + k];
        }
    }
    for (long p = i; p < 32768; p += stride) {
        int l = (int)(p & 63);
        long t = p >> 6;
        int kt = (int)(t & 15), cix = (int)(t >> 4);
        int j = cix * 16 + (l & 15);
        #pragma unroll
        for (int e = 0; e < 8; ++e) {
            int k = kt * 32 + ((l >> 4) << 3) + e;
            wn[p * 8 + e] = (_Float16)Wih[((long)(1024 + j)) * 513 + k];
        }
    }
    for (long p = i; p < 32768; p += stride) {
        int l = (int)(p & 63);
        long t = p >> 6;
        int kt = (int)(t & 15), nt = (int)(t >> 4);
        int n = nt * 16 + (l & 15);
        #pragma unroll
        for (int e = 0; e < 8; ++e) {
            int k = kt * 32 + ((l >> 4) << 3) + e;
            wsls[p * 8 + e] = (_Float16)Ws[(long)k * 512 + n];
        }
    }
    // whB: p = (nt*32 + kt)*64 + l ; B-frag of lh_own (16 N-tiles x 32 K-steps)
    for (long p = i; p < 32768; p += stride) {
        int l = (int)(p & 63);
        long t = p >> 6;
        int kt = (int)(t & 31), nt = (int)(t >> 5);
        int col = nt * 32 + (l & 31);
        #pragma unroll
        for (int e = 0; e < 8; ++e) {
            int k = kt * 16 + ((l >> 5) << 3) + e;
            whb[p * 8 + e] = (_Float16)Wh[(long)k * 512 + col];
        }
    }
    for (long p = i; p < 278528; p += stride) ws[WS_D + p] = 0.0f;
    if (i < 256) ((unsigned*)(ws + WS_BAR))[i] = 0u;
}

// ---------------- main persistent cooperative kernel ----------------
__global__ void __launch_bounds__(NTHREADS, 4) fused_kernel(
        const float* __restrict__ hiddens, const float* __restrict__ allys,
        const float* __restrict__ bs,
        const float* __restrict__ Wo, const float* __restrict__ bo,
        const float* __restrict__ bh,
        const float* __restrict__ b_ih, const float* __restrict__ b_hh,
        const float* __restrict__ Wih,
        const float* __restrict__ W1, const float* __restrict__ b1,
        const float* __restrict__ W2, const float* __restrict__ b2,
        const float* __restrict__ W3, const float* __restrict__ b3,
        const float* __restrict__ W4, const float* __restrict__ b4,
        float* __restrict__ ws, float* __restrict__ out) {
    const int tid = threadIdx.x;

    float* dw  = ws + WS_D;
    float* xw  = ws + WS_X;
    const _Float16* waF  = (const _Float16*)(ws + WS_WA);
    const _Float16* wcF  = (const _Float16*)(ws + WS_WC);
    const _Float16* wnF  = (const _Float16*)(ws + WS_WN);
    const _Float16* wsF  = (const _Float16*)(ws + WS_WS);
    const _Float16* whB  = (const _Float16*)(ws + WS_WHB);
    unsigned* barbase = (unsigned*)(ws + WS_BAR);

    extern __shared__ char smem[];
    char*           xhi   = smem + L_XHI;
    char*           xlo   = smem + L_XLO;
    unsigned short* lsb   = (unsigned short*)(smem + L_LSB);
    float*          ghs   = (float*)(smem + L_GH);
    float*          gis   = (float*)(smem + L_GI);
    float*          lh_s  = (float*)(smem + L_LH);
    float*          wo_s  = (float*)(smem + L_WO);
    float*          e_s   = (float*)(smem + L_E);
    float*          att_s = (float*)(smem + L_ATT);
    float*          h1p   = (float*)(smem + L_H1P);
    float*          h1s   = (float*)(smem + L_H1S);
    float*          h2p   = (float*)(smem + L_H2P);
    float*          h2s   = (float*)(smem + L_H2S);
    float*          h3p   = (float*)(smem + L_H3P);
    int*            misc  = (int*)(smem + L_MISC);
    float*          pbuf  = (float*)(smem + L_PB);

    // ---- dynamic XCD-local grouping (LDS forces 1 block/CU -> 32/XCD) ----
    if (tid == 0) {
        unsigned xcc;
        asm volatile("s_getreg_b32 %0, hwreg(HW_REG_XCC_ID)" : "=s"(xcc));
        int gx = (int)(xcc & 7u);
        unsigned rk = __hip_atomic_fetch_add(barbase + gx * 32 + 1, 1u,
                                             __ATOMIC_RELAXED, __HIP_MEMORY_SCOPE_AGENT);
        misc[0] = gx;
        misc[1] = (int)(rk & 31u);
    }
    __syncthreads();
    const int g = misc[0], cix = misc[1];
    const int myb = g * 32 + cix;
    unsigned* bar = barbase + (g << 5);
    unsigned epoch = 0;

    const int w = tid >> 6, l = tid & 63;
    const int sS = tid & 511;
    const int rowE = tid >> 4, jE = tid & 15;          // gate-epilogue map (tid<512)
    const int jgE = cix * 16 + jE;
    const float* gPanelD = dw + (long)g * GSIZE * RSTRIDE;
    const float* gPanelX = xw + (long)g * GSIZE * RSTRIDE;

    // per-thread k=512 weight column (x-scalar fold)
    float w512r = 0.f, w512z = 0.f, w512n = 0.f;
    if (tid < 512) {
        w512r = Wih[(long)jgE * 513 + 512];
        w512z = Wih[(long)(512 + jgE) * 513 + 512];
        w512n = Wih[(long)(1024 + jgE) * 513 + 512];
    }

    if (tid < NS) wo_s[tid] = Wo[tid];

    // ==== startup: zero panels, then ls = hiddens@Ws + bs via f16 MFMA ====
    for (int i = tid; i < 4416; i += NTHREADS) *(f4v*)(smem + i * 16) = (f4v){0,0,0,0};
    for (int ch = 0; ch < 2; ++ch) {
        __syncthreads();
        {
            const float* src = hiddens + ((long)myb * NT + ch * 24) * NS;
            const int i0 = tid * 12;
            #pragma unroll
            for (int j3 = 0; j3 < 3; ++j3) {
                int idx = i0 + j3 * 4;
                f4v v = *(const f4v*)(src + idx);
                int row = idx >> 9, col = idx & 511;
                h4v h, lo;
                #pragma unroll
                for (int e = 0; e < 4; ++e) { _Float16 hh, ll; split16_(v[e], hh, ll); h[e] = hh; lo[e] = ll; }
                *(h4v*)(xhi + row * XROWB + col * 2) = h;
                *(h4v*)(xlo + row * XROWB + col * 2) = lo;
            }
        }
        __syncthreads();
        lsGemm(smem, wsF, tid, ch, lsb, bs);
    }
    __syncthreads();

    // ==== one-time register-resident data ====
    // waves 0-3: WA; 4-5: WC rz; 6-7: WN n; 8-15: hiddens rows (fp32 bits)
    h8v wreg[16];
    if (w < 4) {
        const _Float16* p = waF + ((long)((cix * 2 + (w & 1)) * 32 + (w >> 1) * 16)) * 512 + (l << 3);
        #pragma unroll
        for (int kt = 0; kt < 16; ++kt) wreg[kt] = *(const h8v*)(p + kt * 512);
    } else if (w < 6) {
        const _Float16* p = wcF + ((long)(cix * 32 + (w - 4) * 16)) * 512 + (l << 3);
        #pragma unroll
        for (int kt = 0; kt < 16; ++kt) wreg[kt] = *(const h8v*)(p + kt * 512);
    } else if (w < 8) {
        const _Float16* p = wnF + ((long)(cix * 16 + (w - 6) * 8)) * 512 + (l << 3);
        #pragma unroll
        for (int kt = 0; kt < 8; ++kt) wreg[kt] = *(const h8v*)(p + kt * 512);
    } else {
        const float* hb = hiddens + (long)myb * NT * NS + sS;
        #pragma unroll
        for (int q = 0; q < 12; ++q) {
            f4v v = { hb[(q * 4 + 0) * 512], hb[(q * 4 + 1) * 512],
                      hb[(q * 4 + 2) * 512], hb[(q * 4 + 3) * 512] };
            wreg[q] = F2H_BITS(v);
        }
    }

    const float bo0 = bo[0];

    // ================= time scan: 2 group barriers per step =================
    for (int t = 0; t < NT; ++t) {
        // ---- merged A+B: stage d; gh MFMA || lh_own MFMA; attention; x store ----
        stagePanel(gPanelD, xhi, xlo, tid);
        __syncthreads();
        DO_GEMMA(true);      // gh -> pbuf/ghs ; lh_own -> lh_s (pre-sync)
        if (tid == 0) cstore1(xw + (long)myb * RSTRIDE + XSLOT, allys[myb * NT + t]);
        {   // e[t'] = sum_s wo[s]*tanh(lh[s]+ls[t'][s]) + bo   (lh_s local!)
            const int wv = tid >> 6, ln = tid & 63;
            for (int q = 0; q < 3; ++q) {
                const int tt = wv * 3 + q;
                float p = 0.f;
                #pragma unroll
                for (int i2 = 0; i2 < 8; ++i2) {
                    int s = ln + (i2 << 6);
                    p = fmaf(wo_s[s], ftanh_(lh_s[s] + hbits2f_(lsb[tt * NS + s])), p);
                }
                #pragma unroll
                for (int off = 32; off >= 1; off >>= 1) p += __shfl_xor(p, off, 64);
                if (ln == 0) e_s[tt] = p + bo0;
            }
        }
        __syncthreads();
        if (tid < 64) {
            float v = (tid < NT) ? e_s[tid] : -1e30f;
            float m = v;
            #pragma unroll
            for (int off = 32; off >= 1; off >>= 1) m = fmaxf(m, __shfl_xor(m, off, 64));
            float ex = (tid < NT) ? __expf(v - m) : 0.0f;
            float ssum = ex;
            #pragma unroll
            for (int off = 32; off >= 1; off >>= 1) ssum += __shfl_xor(ssum, off, 64);
            if (tid < NT) att_s[tid] = ex * frcp_(ssum);
        }
        __syncthreads();
        if (tid >= 512) {   // c[s] on hiddens-holding waves (fp32 in wreg bits)
            float c = 0.f;
            #pragma unroll
            for (int q = 0; q < 12; ++q) {
                f4v hv = H2F_BITS(wreg[q]);
                c = fmaf(att_s[q * 4 + 0], hv.x, c);
                c = fmaf(att_s[q * 4 + 1], hv.y, c);
                c = fmaf(att_s[q * 4 + 2], hv.z, c);
                c = fmaf(att_s[q * 4 + 3], hv.w, c);
            }
            cstore1(xw + (long)myb * RSTRIDE + sS, c);
        }
        gbar(bar, &epoch);

        // ---- C: stage x -> panels; MFMA gi; GRU gates ----
        float hp = 0.f;
        if (tid < 512) hp = cload1(dw + (long)(g * 32 + rowE) * RSTRIDE + jgE);
        stagePanel(gPanelX, xhi, xlo, tid);
        __syncthreads();
        DO_GEMMC();
        __syncthreads();
        if (tid < 512) {
            float x512f = (float)*(const _Float16*)(xhi + rowE * XROWB + 1024)
                        + (float)*(const _Float16*)(xlo + rowE * XROWB + 1024);
            float gr  = fmaf(x512f, w512r, gis[rowE * 17 + jE]        + ghs[rowE * 17 + jE]);
            float gz  = fmaf(x512f, w512z, gis[544 + rowE * 17 + jE]  + ghs[544 + rowE * 17 + jE]);
            float gni = fmaf(x512f, w512n, gis[1088 + rowE * 17 + jE]);
            float gnh = ghs[1088 + rowE * 17 + jE];
            float rg = fsig_(gr);
            float zg = fsig_(gz);
            float ng = ftanh_(fmaf(rg, gnh, gni));
            cstore1(dw + (long)(g * 32 + rowE) * RSTRIDE + jgE, (1.f - zg) * ng + zg * hp);
        }
        gbar(bar, &epoch);
    }

    // ================= k_wk_ahead head =================
    for (int kk = 0; kk < KAHEAD; ++kk) {
        {
            float v = 0.f;
            if (tid < NS) v = cload1(dw + (long)myb * RSTRIDE + tid);
            cwait();
            if (tid < NS) lh_s[tid] = v;
        }
        __syncthreads();
        {   // M1: 512 -> 256
            int n = tid & 255, q4 = tid >> 8;
            const float* av = lh_s + q4 * 128;
            const float* wp = W1 + (long)(q4 * 128) * 256 + n;
            float acc = 0.f;
            #pragma unroll 4
            for (int k2 = 0; k2 < 128; ++k2) { acc = fmaf(av[k2], wp[0], acc); wp += 256; }
            h1p[n * 4 + q4] = acc;
        }
        __syncthreads();
        if (tid < 256) {
            float v = h1p[tid * 4] + h1p[tid * 4 + 1] + h1p[tid * 4 + 2] + h1p[tid * 4 + 3];
            h1s[tid] = lrelu_(v + b1[tid]);
        }
        __syncthreads();
        if (tid < 512) {   // M2: 256 -> 128
            int n = tid & 127, q4 = tid >> 7;
            const float* av = h1s + q4 * 64;
            const float* wp = W2 + (long)(q4 * 64) * 128 + n;
            float acc = 0.f;
            #pragma unroll 4
            for (int k2 = 0; k2 < 64; ++k2) { acc = fmaf(av[k2], wp[0], acc); wp += 128; }
            h2p[n * 4 + q4] = acc;
        }
        __syncthreads();
        if (tid < 128) {
            float v = h2p[tid * 4] + h2p[tid * 4 + 1] + h2p[tid * 4 + 2] + h2p[tid * 4 + 3];
            h2s[tid] = lrelu_(v + b2[tid]);
        }
        __syncthreads();
        if (tid < 256) {   // M3: 128 -> 64
            int n = tid & 63, q4 = tid >> 6;
            const float* av = h2s + q4 * 32;
            const float* wp = W3 + (long)(q4 * 32) * 64 + n;
            float acc = 0.f;
            #pragma unroll 4
            for (int k2 = 0; k2 < 32; ++k2) { acc = fmaf(av[k2], wp[0], acc); wp += 64; }
            h3p[n * 4 + q4] = acc;
        }
        __syncthreads();
        if (tid < 64) {    // M3 epilogue + M4
            float v = h3p[tid * 4] + h3p[tid * 4 + 1] + h3p[tid * 4 + 2] + h3p[tid * 4 + 3];
            float h3v = lrelu_(v + b3[tid]);
            float p = h3v * W4[tid];
            #pragma unroll
            for (int off = 32; off >= 1; off >>= 1) p += __shfl_xor(p, off, 64);
            if (tid == 0) {
                float o = lrelu_(p + b4[0]);
                out[myb * KAHEAD + kk] = o;
                cstore1(xw + (long)myb * RSTRIDE + XSLOT, o);
            }
        }
        if (kk < KAHEAD - 1) {
            gbar(bar, &epoch);
            float hp = 0.f;
            if (tid < 512) hp = cload1(dw + (long)(g * 32 + rowE) * RSTRIDE + jgE);
            stagePanel(gPanelD, xhi, xlo, tid);
            __syncthreads();
            DO_GEMMA(false);
            __syncthreads();
            stagePanel(gPanelX, xhi, xlo, tid);
            __syncthreads();
            DO_GEMMC();
            __syncthreads();
            if (tid < 512) {
                float x512f = (float)*(const _Float16*)(xhi + rowE * XROWB + 1024)
                            + (float)*(const _Float16*)(xlo + rowE * XROWB + 1024);
                float gr  = fmaf(x512f, w512r, gis[rowE * 17 + jE]        + ghs[rowE * 17 + jE]);
                float gz  = fmaf(x512f, w512z, gis[544 + rowE * 17 + jE]  + ghs[544 + rowE * 17 + jE]);
                float gni = fmaf(x512f, w512n, gis[1088 + rowE * 17 + jE]);
                float gnh = ghs[1088 + rowE * 17 + jE];
                float rg = fsig_(gr);
                float zg = fsig_(gz);
                float ng = ftanh_(fmaf(rg, gnh, gni));
                cstore1(dw + (long)(g * 32 + rowE) * RSTRIDE + jgE, (1.f - zg) * ng + zg * hp);
            }
            gbar(bar, &epoch);
        }
    }
}

// ---------------- host ----------------
extern "C" void kernel_launch(void* const* d_in, const int* in_sizes, int n_in,
                              void* d_out, int out_size, void* d_ws, size_t ws_size,
                              hipStream_t stream) {
    const float* hiddens = (const float*)d_in[0];
    const float* allys   = (const float*)d_in[1];
    const float* Wh   = (const float*)d_in[3];
    const float* bh   = (const float*)d_in[4];
    const float* Ws   = (const float*)d_in[5];
    const float* bs   = (const float*)d_in[6];
    const float* Wo   = (const float*)d_in[7];
    const float* bo   = (const float*)d_in[8];
    const float* W_ih = (const float*)d_in[9];
    const float* W_hh = (const float*)d_in[10];
    const float* b_ih = (const float*)d_in[11];
    const float* b_hh = (const float*)d_in[12];
    const float* W1 = (const float*)d_in[13];
    const float* b1 = (const float*)d_in[14];
    const float* W2 = (const float*)d_in[15];
    const float* b2 = (const float*)d_in[16];
    const float* W3 = (const float*)d_in[17];
    const float* b3 = (const float*)d_in[18];
    const float* W4 = (const float*)d_in[19];
    const float* b4 = (const float*)d_in[20];
    float* wsf = (float*)d_ws;
    float* outf = (float*)d_out;

    if (ws_size < (size_t)WS_FLOATS * sizeof(float)) {
        fprintf(stderr, "kernel_launch: workspace too small (%zu < %zu)\n",
                ws_size, (size_t)WS_FLOATS * sizeof(float));
        return;
    }

    prep_kernel<<<dim3(2048), dim3(256), 0, stream>>>(W_hh, W_ih, Wh, Ws, wsf);

    (void)hipFuncSetAttribute((const void*)fused_kernel,
                              hipFuncAttributeMaxDynamicSharedMemorySize, LDS_BYTES);

    void* args[] = { &hiddens, &allys, &bs, &Wo, &bo, &bh,
                     &b_ih, &b_hh, &W_ih, &W1, &b1, &W2, &b2, &W3, &b3, &W4, &b4,
                     &wsf, &outf };
    hipError_t e = hipLaunchCooperativeKernel((void*)fused_kernel,
                                              dim3(NBLOCKS), dim3(NTHREADS),
                                              args, LDS_BYTES, stream);
    if (e != hipSuccess) {
        fprintf(stderr, "coop launch failed (%d); plain fallback\n", (int)e);
        (void)hipGetLastError();
        fused_kernel<<<dim3(NBLOCKS), dim3(NTHREADS), LDS_BYTES, stream>>>(
            hiddens, allys, bs, Wo, bo, bh, b_ih, b_hh, W_ih,
            W1, b1, W2, b2, W3, b3, W4, b4, wsf, outf);
    }
}

// Round 17
// 1679.897 us; speedup vs baseline: 1.2335x; 1.2335x over previous
//
#include <hip/hip_runtime.h>
#include <cstdio>

#ifndef __has_builtin
#define __has_builtin(x) 0
#endif

// ---------------- problem constants ----------------
#define NB      256
#define NT      48
#define NS      512
#define KAHEAD  4
#define NTHREADS 1024
#define NBLOCKS  256
#define GSIZE    32
#define RSTRIDE  544     // exchange row floats (512 d / 513 x used)
#define XSLOT    512     // x scalar slot
#define XROWB    1104    // LDS f16 panel row stride bytes (69 quads: conflict-free)

// ---------------- workspace (float offsets) ----------------
#define WS_D     0              // [256][544] d exchange fp32
#define WS_X     139264         // [256][544] x exchange
#define WS_LH    278528         // [256][512] lh exchange
#define WS_BAR   409600         // 256 uints
#define WS_WA    409856         // f16 [32 cix][2 nt][32 kt][512]
#define WS_WC    934144         // f16 [32 cix][32 kt][512]
#define WS_WN    1196288        // f16 [32 cix][16 kt][512]
#define WS_WS    1327360        // f16 [32 nt][16 kt][512]
#define WS_FLOATS 1458432       // 5.83 MB

// ---------------- LDS (byte offsets), total 156432 ----------------
#define L_XHI    0              // f16 panel hi [32][1104B] 35328
#define L_XLO    35328
#define L_LSB    70656          // ushort [48][512] f16 ls 49152
#define L_GH     119808         // float [3][32][17]
#define L_GI     126336
#define L_LH     132864         // float [512]
#define L_WO     134912
#define L_E      136960
#define L_ATT    137216
#define L_H1P    139520
#define L_H1S    143616
#define L_H2P    144640
#define L_H2S    146688
#define L_H3P    147200
#define L_MISC   148224
#define L_PB     148240         // float[2048] K-split partial buffer (8KB)
#define LDS_BYTES 156432

typedef float    f4v  __attribute__((ext_vector_type(4)));
typedef float    f16v __attribute__((ext_vector_type(16)));
typedef _Float16 h4v  __attribute__((ext_vector_type(4)));
typedef _Float16 h8v  __attribute__((ext_vector_type(8)));

// ---------------- MFMA (f16) ----------------
__device__ __forceinline__ f16v MFMA32(h8v a, h8v b, f16v c) {
    return __builtin_amdgcn_mfma_f32_32x32x16_f16(a, b, c, 0, 0, 0);
}
__device__ __forceinline__ f4v MFMA16(h8v a, h8v b, f4v c) {
    return __builtin_amdgcn_mfma_f32_16x16x32_f16(a, b, c, 0, 0, 0);
}

#if __has_builtin(__builtin_bit_cast)
#define F2H_BITS(v) __builtin_bit_cast(h8v, (v))
#define H2F_BITS(v) __builtin_bit_cast(f4v, (v))
#else
__device__ __forceinline__ h8v f2h_bits_(f4v v) { union { f4v f; h8v h; } u; u.f = v; return u.h; }
__device__ __forceinline__ f4v h2f_bits_(h8v v) { union { f4v f; h8v h; } u; u.h = v; return u.f; }
#define F2H_BITS(v) f2h_bits_(v)
#define H2F_BITS(v) h2f_bits_(v)
#endif

// ---------------- math ----------------
__device__ __forceinline__ float frcp_(float x) {
#if __has_builtin(__builtin_amdgcn_rcpf)
    return __builtin_amdgcn_rcpf(x);
#else
    return 1.0f / x;
#endif
}
__device__ __forceinline__ float ftanh_(float x) {
    float e = __expf(2.0f * x);
    return 1.0f - 2.0f * frcp_(e + 1.0f);
}
__device__ __forceinline__ float fsig_(float x) { return frcp_(1.0f + __expf(-x)); }
__device__ __forceinline__ float lrelu_(float x) { return fmaxf(x, 0.01f * x); }
__device__ __forceinline__ void split16_(float v, _Float16& hi, _Float16& lo) {
    _Float16 h = (_Float16)v;
    hi = h;
    lo = (_Float16)(v - (float)h);
}
__device__ __forceinline__ unsigned short f2hbits_(float v) {
    union { _Float16 h; unsigned short u; } c; c.h = (_Float16)v; return c.u;
}
__device__ __forceinline__ float hbits2f_(unsigned short u) {
    union { unsigned short u; _Float16 h; } c; c.u = u; return (float)c.h;
}

// ---------------- XCD-local (L2) coherent access: sc0 = L1-bypass ----------------
__device__ __forceinline__ void cstore1(float* p, float v) {
    asm volatile("global_store_dword %0, %1, off sc0" :: "v"(p), "v"(v) : "memory");
}
__device__ __forceinline__ f4v cload4(const float* p) {
    f4v v;
    asm volatile("global_load_dwordx4 %0, %1, off sc0" : "=v"(v) : "v"(p));
    return v;
}
__device__ __forceinline__ float cload1(const float* p) {
    float v;
    asm volatile("global_load_dword %0, %1, off sc0" : "=v"(v) : "v"(p));
    return v;
}
__device__ __forceinline__ void cwait() {
    asm volatile("s_waitcnt vmcnt(0)" ::: "memory");
    __builtin_amdgcn_sched_barrier(0);
}

// Group barrier: proven __hip_atomic AGENT-scope pair (r5-r8, r12, r14 at floor).
// Confirmed load-bearing: r9 (asm atomic), r11, r16 (plain-flag) all raced —
// cross-CU visibility is only reliably established by this atomic pair.
__device__ __forceinline__ void gbar(unsigned* bar, unsigned* epoch) {
    asm volatile("s_waitcnt vmcnt(0)" ::: "memory");
    __syncthreads();
    if (threadIdx.x == 0) {
        *epoch += GSIZE;
        __hip_atomic_fetch_add(bar, 1u, __ATOMIC_RELAXED, __HIP_MEMORY_SCOPE_AGENT);
        unsigned target = *epoch;
        int guard = 0;
        while (__hip_atomic_load(bar, __ATOMIC_RELAXED, __HIP_MEMORY_SCOPE_AGENT) < target) {
#if __has_builtin(__builtin_amdgcn_s_sleep)
            __builtin_amdgcn_s_sleep(1);
#endif
            if (++guard > (1 << 17)) break;
        }
    }
    __syncthreads();
}

// ---------------- staging: fp32 exchange panel -> LDS f16 hi/lo ----------------
__device__ __forceinline__ void cvtStore_(char* hiB, char* loB, int idx, f4v v) {
    unsigned row = (unsigned)idx / 544u;
    unsigned col = (unsigned)idx - row * 544u;
    h4v h, l;
    #pragma unroll
    for (int i = 0; i < 4; ++i) { _Float16 hh, ll; split16_(v[i], hh, ll); h[i] = hh; l[i] = ll; }
    *(h4v*)(hiB + row * XROWB + col * 2) = h;
    *(h4v*)(loB + row * XROWB + col * 2) = l;
}
__device__ __forceinline__ void stagePanel(const float* __restrict__ gsrc,
                                           char* __restrict__ hiB,
                                           char* __restrict__ loB, int tid) {
    f4v v0 = cload4(gsrc + tid * 4);
    f4v v1 = cload4(gsrc + 4096 + tid * 4);
    f4v v2 = cload4(gsrc + 8192 + tid * 4);
    f4v v3 = cload4(gsrc + 12288 + tid * 4);
    f4v v4 = {0.f, 0.f, 0.f, 0.f};
    if (tid < 256) v4 = cload4(gsrc + 16384 + tid * 4);
    cwait();
    cvtStore_(hiB, loB, tid * 4, v0);
    cvtStore_(hiB, loB, 4096 + tid * 4, v1);
    cvtStore_(hiB, loB, 8192 + tid * 4, v2);
    cvtStore_(hiB, loB, 12288 + tid * 4, v3);
    if (tid < 256) cvtStore_(hiB, loB, 16384 + tid * 4, v4);
}

// ---------------- GEMMs with register-resident B (macros: guaranteed inline) ----------------
// waves 0-3: gemmA (nt2=w&1, kc=w>>1); single-f16 B (r8-proven); internal sync.
#define DO_GEMMA(doLH) do {                                                          \
    f16v acc_ = (f16v){0,0,0,0,0,0,0,0,0,0,0,0,0,0,0,0};                             \
    if (w < 4) {                                                                     \
        const int kc_ = w >> 1;                                                      \
        const int aoff_ = (l & 31) * XROWB + ((l >> 5) << 4);                        \
        _Pragma("unroll")                                                            \
        for (int kt = 0; kt < 16; ++kt) {                                            \
            h8v ah = *(const h8v*)(smem + L_XHI + aoff_ + (kc_ * 16 + kt) * 32);     \
            h8v al = *(const h8v*)(smem + L_XLO + aoff_ + (kc_ * 16 + kt) * 32);     \
            acc_ = MFMA32(ah, wreg[kt], acc_);                                       \
            acc_ = MFMA32(al, wreg[kt], acc_);                                       \
        }                                                                            \
        if (kc_ == 1) {                                                              \
            _Pragma("unroll")                                                        \
            for (int r = 0; r < 16; ++r) pbuf[(w & 1) * 1024 + r * 64 + l] = acc_[r];\
        }                                                                            \
    }                                                                                \
    __syncthreads();                                                                 \
    if (w < 2) {                                                                     \
        _Pragma("unroll")                                                            \
        for (int r = 0; r < 16; ++r) acc_[r] += pbuf[w * 1024 + r * 64 + l];         \
        const int c_ = w * 32 + (l & 31);                                            \
        const int rb_ = (l >> 5) << 2;                                               \
        if (c_ < 16) {                                                               \
            if (doLH) {                                                              \
                const int j_ = cix * 16 + c_;                                        \
                const float bb_ = bh[j_];                                            \
                _Pragma("unroll")                                                    \
                for (int r = 0; r < 16; ++r) {                                       \
                    int row_ = (r & 3) + ((r >> 2) << 3) + rb_;                      \
                    cstore1(lhw + (long)(g * 32 + row_) * NS + j_, acc_[r] + bb_);   \
                }                                                                    \
            }                                                                        \
        } else {                                                                     \
            const int gate_ = (c_ - 16) >> 4, jj_ = (c_ - 16) & 15;                  \
            const float bb_ = b_hh[gate_ * 512 + cix * 16 + jj_];                    \
            _Pragma("unroll")                                                        \
            for (int r = 0; r < 16; ++r) {                                           \
                int row_ = (r & 3) + ((r >> 2) << 3) + rb_;                          \
                ghs[gate_ * 544 + row_ * 17 + jj_] = acc_[r] + bb_;                  \
            }                                                                        \
        }                                                                            \
    }                                                                                \
} while (0)

// waves 4-5: rz (kc=w-4); waves 6-7: n (kc=w-6); internal __syncthreads for all
#define DO_GEMMC() do {                                                              \
    f16v acc_ = (f16v){0,0,0,0,0,0,0,0,0,0,0,0,0,0,0,0};                             \
    f4v an0_ = {0.f,0.f,0.f,0.f}, an1_ = {0.f,0.f,0.f,0.f};                          \
    if (w == 4 || w == 5) {                                                          \
        const int kc_ = w - 4;                                                       \
        const int aoff_ = (l & 31) * XROWB + ((l >> 5) << 4);                        \
        _Pragma("unroll")                                                            \
        for (int kt = 0; kt < 16; ++kt) {                                            \
            h8v ah = *(const h8v*)(smem + L_XHI + aoff_ + (kc_ * 16 + kt) * 32);     \
            h8v al = *(const h8v*)(smem + L_XLO + aoff_ + (kc_ * 16 + kt) * 32);     \
            acc_ = MFMA32(ah, wreg[kt], acc_);                                       \
            acc_ = MFMA32(al, wreg[kt], acc_);                                       \
        }                                                                            \
        if (kc_ == 1) {                                                              \
            _Pragma("unroll")                                                        \
            for (int r = 0; r < 16; ++r) pbuf[r * 64 + l] = acc_[r];                 \
        }                                                                            \
    } else if (w == 6 || w == 7) {                                                   \
        const int kc_ = w - 6;                                                       \
        const int a0_ = (l & 15) * XROWB + ((l >> 4) << 4);                          \
        const int a1_ = a0_ + 16 * XROWB;                                            \
        _Pragma("unroll")                                                            \
        for (int kt = 0; kt < 8; ++kt) {                                             \
            const int kb_ = (kc_ * 8 + kt) * 64;                                     \
            h8v ah0 = *(const h8v*)(smem + L_XHI + a0_ + kb_);                       \
            h8v al0 = *(const h8v*)(smem + L_XLO + a0_ + kb_);                       \
            h8v ah1 = *(const h8v*)(smem + L_XHI + a1_ + kb_);                       \
            h8v al1 = *(const h8v*)(smem + L_XLO + a1_ + kb_);                       \
            an0_ = MFMA16(ah0, wreg[kt], an0_); an0_ = MFMA16(al0, wreg[kt], an0_);  \
            an1_ = MFMA16(ah1, wreg[kt], an1_); an1_ = MFMA16(al1, wreg[kt], an1_);  \
        }                                                                            \
        if (kc_ == 1) {                                                              \
            _Pragma("unroll")                                                        \
            for (int r = 0; r < 4; ++r) {                                            \
                pbuf[1024 + r * 64 + l] = an0_[r];                                   \
                pbuf[1280 + r * 64 + l] = an1_[r];                                   \
            }                                                                        \
        }                                                                            \
    }                                                                                \
    __syncthreads();                                                                 \
    if (w == 4) {                                                                    \
        _Pragma("unroll")                                                            \
        for (int r = 0; r < 16; ++r) acc_[r] += pbuf[r * 64 + l];                    \
        const int c_ = l & 31, gate_ = c_ >> 4, jj_ = c_ & 15;                       \
        const int rb_ = (l >> 5) << 2;                                               \
        const float bb_ = b_ih[gate_ * 512 + cix * 16 + jj_];                        \
        _Pragma("unroll")                                                            \
        for (int r = 0; r < 16; ++r) {                                               \
            int row_ = (r & 3) + ((r >> 2) << 3) + rb_;                              \
            gis[gate_ * 544 + row_ * 17 + jj_] = acc_[r] + bb_;                      \
        }                                                                            \
    } else if (w == 6) {                                                             \
        const int jj_ = l & 15;                                                      \
        const float bb_ = b_ih[1024 + cix * 16 + jj_];                               \
        _Pragma("unroll")                                                            \
        for (int r = 0; r < 4; ++r) {                                                \
            int row_ = ((l >> 4) << 2) + r;                                          \
            gis[1088 + row_ * 17 + jj_] = an0_[r] + pbuf[1024 + r * 64 + l] + bb_;   \
            gis[1088 + (16 + row_) * 17 + jj_] = an1_[r] + pbuf[1280 + r * 64 + l] + bb_; \
        }                                                                            \
    }                                                                                \
} while (0)

// startup ls GEMM: 16 waves, 16x16x32_f16, K=512; ls stored f16
__device__ __forceinline__ void lsGemm(const char* smem, const _Float16* WS_,
        int tid, int ch, unsigned short* lsb, const float* bs) {
    const int w = tid >> 6, l = tid & 63;
    const int mt = w & 1, ng = w >> 1;
    const int aoff = (mt * 16 + (l & 15)) * XROWB + ((l >> 4) << 4);
    f4v acc[4] = {{0,0,0,0},{0,0,0,0},{0,0,0,0},{0,0,0,0}};
    for (int kt = 0; kt < 16; ++kt) {
        h8v ah = *(const h8v*)(smem + L_XHI + aoff + kt * 64);
        h8v al = *(const h8v*)(smem + L_XLO + aoff + kt * 64);
        #pragma unroll
        for (int i = 0; i < 4; ++i) {
            const _Float16* bp = WS_ + ((long)((ng * 4 + i) * 16 + kt)) * 512 + (l << 3);
            h8v bb = *(const h8v*)bp;
            acc[i] = MFMA16(ah, bb, acc[i]);
            acc[i] = MFMA16(al, bb, acc[i]);
        }
    }
    #pragma unroll
    for (int i = 0; i < 4; ++i) {
        const int n = (ng * 4 + i) * 16 + (l & 15);
        const float bsv = bs[n];
        #pragma unroll
        for (int r = 0; r < 4; ++r) {
            int row = mt * 16 + ((l >> 4) << 2) + r;
            if (row < 24)
                lsb[(ch * 24 + row) * NS + n] = f2hbits_(acc[i][r] + bsv);
        }
    }
}

// ---------------- prep: f16 fragment packing + zeroing ----------------
__global__ void prep_kernel(const float* __restrict__ Whh,
                            const float* __restrict__ Wih,
                            const float* __restrict__ Wh,
                            const float* __restrict__ Ws,
                            float* __restrict__ ws) {
    long i = (long)blockIdx.x * blockDim.x + threadIdx.x;
    long stride = (long)gridDim.x * blockDim.x;
    _Float16* wa  = (_Float16*)(ws + WS_WA);
    _Float16* wc  = (_Float16*)(ws + WS_WC);
    _Float16* wn  = (_Float16*)(ws + WS_WN);
    _Float16* wsls = (_Float16*)(ws + WS_WS);

    for (long p = i; p < 131072; p += stride) {
        int l = (int)(p & 63);
        long t = p >> 6;
        int kt = (int)(t & 31);
        int u = (int)(t >> 5);
        int nt = u & 1, cix = u >> 1;
        int c = nt * 32 + (l & 31);
        #pragma unroll
        for (int e = 0; e < 8; ++e) {
            int k = kt * 16 + ((l >> 5) << 3) + e;
            float wv;
            if (c < 16) wv = Wh[(long)k * 512 + cix * 16 + c];
            else {
                int gate = (c - 16) >> 4, j = cix * 16 + ((c - 16) & 15);
                wv = Whh[((long)(gate * 512 + j)) * 512 + k];
            }
            wa[p * 8 + e] = (_Float16)wv;
        }
    }
    for (long p = i; p < 65536; p += stride) {
        int l = (int)(p & 63);
        long t = p >> 6;
        int kt = (int)(t & 31), cix = (int)(t >> 5);
        int c = l & 31, gate = c >> 4, j = cix * 16 + (c & 15);
        #pragma unroll
        for (int e = 0; e < 8; ++e) {
            int k = kt * 16 + ((l >> 5) << 3) + e;
            wc[p * 8 + e] = (_Float16)Wih[((long)(gate * 512 + j)) * 513 + k];
        }
    }
    for (long p = i; p < 32768; p += stride) {
        int l = (int)(p & 63);
        long t = p >> 6;
        int kt = (int)(t & 15), cix = (int)(t >> 4);
        int j = cix * 16 + (l & 15);
        #pragma unroll
        for (int e = 0; e < 8; ++e) {
            int k = kt * 32 + ((l >> 4) << 3) + e;
            wn[p * 8 + e] = (_Float16)Wih[((long)(1024 + j)) * 513 + k];
        }
    }
    for (long p = i; p < 32768; p += stride) {
        int l = (int)(p & 63);
        long t = p >> 6;
        int kt = (int)(t & 15), nt = (int)(t >> 4);
        int n = nt * 16 + (l & 15);
        #pragma unroll
        for (int e = 0; e < 8; ++e) {
            int k = kt * 32 + ((l >> 4) << 3) + e;
            wsls[p * 8 + e] = (_Float16)Ws[(long)k * 512 + n];
        }
    }
    for (long p = i; p < 278528; p += stride) ws[WS_D + p] = 0.0f;
    if (i < 256) ((unsigned*)(ws + WS_BAR))[i] = 0u;
}

// ---------------- main persistent cooperative kernel ----------------
__global__ void __launch_bounds__(NTHREADS, 4) fused_kernel(
        const float* __restrict__ hiddens, const float* __restrict__ allys,
        const float* __restrict__ bs,
        const float* __restrict__ Wo, const float* __restrict__ bo,
        const float* __restrict__ bh,
        const float* __restrict__ b_ih, const float* __restrict__ b_hh,
        const float* __restrict__ Wih,
        const float* __restrict__ W1, const float* __restrict__ b1,
        const float* __restrict__ W2, const float* __restrict__ b2,
        const float* __restrict__ W3, const float* __restrict__ b3,
        const float* __restrict__ W4, const float* __restrict__ b4,
        float* __restrict__ ws, float* __restrict__ out) {
    const int tid = threadIdx.x;

    float* dw  = ws + WS_D;
    float* xw  = ws + WS_X;
    float* lhw = ws + WS_LH;
    const _Float16* waF  = (const _Float16*)(ws + WS_WA);
    const _Float16* wcF  = (const _Float16*)(ws + WS_WC);
    const _Float16* wnF  = (const _Float16*)(ws + WS_WN);
    const _Float16* wsF  = (const _Float16*)(ws + WS_WS);
    unsigned* barbase = (unsigned*)(ws + WS_BAR);

    extern __shared__ char smem[];
    char*           xhi   = smem + L_XHI;
    char*           xlo   = smem + L_XLO;
    unsigned short* lsb   = (unsigned short*)(smem + L_LSB);
    float*          ghs   = (float*)(smem + L_GH);
    float*          gis   = (float*)(smem + L_GI);
    float*          lh_s  = (float*)(smem + L_LH);
    float*          wo_s  = (float*)(smem + L_WO);
    float*          e_s   = (float*)(smem + L_E);
    float*          att_s = (float*)(smem + L_ATT);
    float*          h1p   = (float*)(smem + L_H1P);
    float*          h1s   = (float*)(smem + L_H1S);
    float*          h2p   = (float*)(smem + L_H2P);
    float*          h2s   = (float*)(smem + L_H2S);
    float*          h3p   = (float*)(smem + L_H3P);
    int*            misc  = (int*)(smem + L_MISC);
    float*          pbuf  = (float*)(smem + L_PB);

    // ---- dynamic XCD-local grouping (LDS forces 1 block/CU -> 32/XCD) ----
    if (tid == 0) {
        unsigned xcc;
        asm volatile("s_getreg_b32 %0, hwreg(HW_REG_XCC_ID)" : "=s"(xcc));
        int gx = (int)(xcc & 7u);
        unsigned rk = __hip_atomic_fetch_add(barbase + gx * 32 + 1, 1u,
                                             __ATOMIC_RELAXED, __HIP_MEMORY_SCOPE_AGENT);
        misc[0] = gx;
        misc[1] = (int)(rk & 31u);
    }
    __syncthreads();
    const int g = misc[0], cix = misc[1];
    const int myb = g * 32 + cix;
    unsigned* bar = barbase + (g << 5);
    unsigned epoch = 0;

    const int w = tid >> 6, l = tid & 63;
    const int sS = tid & 511;
    const int rowE = tid >> 4, jE = tid & 15;          // gate-epilogue map (tid<512)
    const int jgE = cix * 16 + jE;
    const float* gPanelD = dw + (long)g * GSIZE * RSTRIDE;
    const float* gPanelX = xw + (long)g * GSIZE * RSTRIDE;

    // per-thread k=512 weight column (x-scalar fold)
    float w512r = 0.f, w512z = 0.f, w512n = 0.f;
    if (tid < 512) {
        w512r = Wih[(long)jgE * 513 + 512];
        w512z = Wih[(long)(512 + jgE) * 513 + 512];
        w512n = Wih[(long)(1024 + jgE) * 513 + 512];
    }

    if (tid < NS) wo_s[tid] = Wo[tid];

    // ==== startup: zero panels, then ls = hiddens@Ws + bs via f16 MFMA ====
    for (int i = tid; i < 4416; i += NTHREADS) *(f4v*)(smem + i * 16) = (f4v){0,0,0,0};
    for (int ch = 0; ch < 2; ++ch) {
        __syncthreads();
        {
            const float* src = hiddens + ((long)myb * NT + ch * 24) * NS;
            const int i0 = tid * 12;
            #pragma unroll
            for (int j3 = 0; j3 < 3; ++j3) {
                int idx = i0 + j3 * 4;
                f4v v = *(const f4v*)(src + idx);
                int row = idx >> 9, col = idx & 511;
                h4v h, lo;
                #pragma unroll
                for (int e = 0; e < 4; ++e) { _Float16 hh, ll; split16_(v[e], hh, ll); h[e] = hh; lo[e] = ll; }
                *(h4v*)(xhi + row * XROWB + col * 2) = h;
                *(h4v*)(xlo + row * XROWB + col * 2) = lo;
            }
        }
        __syncthreads();
        lsGemm(smem, wsF, tid, ch, lsb, bs);
    }
    __syncthreads();

    // ==== one-time register-resident data ====
    // waves 0-3: WA; 4-5: WC rz; 6-7: WN n; 8-15: hiddens rows (fp32 bits)
    h8v wreg[16];
    if (w < 4) {
        const _Float16* p = waF + ((long)((cix * 2 + (w & 1)) * 32 + (w >> 1) * 16)) * 512 + (l << 3);
        #pragma unroll
        for (int kt = 0; kt < 16; ++kt) wreg[kt] = *(const h8v*)(p + kt * 512);
    } else if (w < 6) {
        const _Float16* p = wcF + ((long)(cix * 32 + (w - 4) * 16)) * 512 + (l << 3);
        #pragma unroll
        for (int kt = 0; kt < 16; ++kt) wreg[kt] = *(const h8v*)(p + kt * 512);
    } else if (w < 8) {
        const _Float16* p = wnF + ((long)(cix * 16 + (w - 6) * 8)) * 512 + (l << 3);
        #pragma unroll
        for (int kt = 0; kt < 8; ++kt) wreg[kt] = *(const h8v*)(p + kt * 512);
    } else {
        const float* hb = hiddens + (long)myb * NT * NS + sS;
        #pragma unroll
        for (int q = 0; q < 12; ++q) {
            f4v v = { hb[(q * 4 + 0) * 512], hb[(q * 4 + 1) * 512],
                      hb[(q * 4 + 2) * 512], hb[(q * 4 + 3) * 512] };
            wreg[q] = F2H_BITS(v);
        }
    }

    const float bo0 = bo[0];

    // ================= time scan: 3 group barriers per step =================
    for (int t = 0; t < NT; ++t) {
        // ---- A: stage d -> panels; MFMA gh + lh ----
        stagePanel(gPanelD, xhi, xlo, tid);
        __syncthreads();
        DO_GEMMA(true);
        gbar(bar, &epoch);

        // ---- B: attention for own row ----
        if (tid < 128) {
            f4v v = cload4(lhw + (long)myb * NS + tid * 4);
            cwait();
            *(f4v*)(lh_s + tid * 4) = v;
        }
        if (tid == 0) cstore1(xw + (long)myb * RSTRIDE + XSLOT, allys[myb * NT + t]);
        __syncthreads();
        {
            const int wv = tid >> 6, ln = tid & 63;
            for (int q = 0; q < 3; ++q) {
                const int tt = wv * 3 + q;
                float p = 0.f;
                #pragma unroll
                for (int i2 = 0; i2 < 8; ++i2) {
                    int s = ln + (i2 << 6);
                    p = fmaf(wo_s[s], ftanh_(lh_s[s] + hbits2f_(lsb[tt * NS + s])), p);
                }
                #pragma unroll
                for (int off = 32; off >= 1; off >>= 1) p += __shfl_xor(p, off, 64);
                if (ln == 0) e_s[tt] = p + bo0;
            }
        }
        __syncthreads();
        if (tid < 64) {
            float v = (tid < NT) ? e_s[tid] : -1e30f;
            float m = v;
            #pragma unroll
            for (int off = 32; off >= 1; off >>= 1) m = fmaxf(m, __shfl_xor(m, off, 64));
            float ex = (tid < NT) ? __expf(v - m) : 0.0f;
            float ssum = ex;
            #pragma unroll
            for (int off = 32; off >= 1; off >>= 1) ssum += __shfl_xor(ssum, off, 64);
            if (tid < NT) att_s[tid] = ex * frcp_(ssum);
        }
        __syncthreads();
        if (tid >= 512) {   // c[s] on hiddens-holding waves (fp32 in wreg bits)
            float c = 0.f;
            #pragma unroll
            for (int q = 0; q < 12; ++q) {
                f4v hv = H2F_BITS(wreg[q]);
                c = fmaf(att_s[q * 4 + 0], hv.x, c);
                c = fmaf(att_s[q * 4 + 1], hv.y, c);
                c = fmaf(att_s[q * 4 + 2], hv.z, c);
                c = fmaf(att_s[q * 4 + 3], hv.w, c);
            }
            cstore1(xw + (long)myb * RSTRIDE + sS, c);
        }
        gbar(bar, &epoch);

        // ---- C: stage x -> panels; MFMA gi; GRU gates ----
        float hp = 0.f;
        if (tid < 512) hp = cload1(dw + (long)(g * 32 + rowE) * RSTRIDE + jgE);
        stagePanel(gPanelX, xhi, xlo, tid);
        __syncthreads();
        DO_GEMMC();
        __syncthreads();
        if (tid < 512) {
            float x512f = (float)*(const _Float16*)(xhi + rowE * XROWB + 1024)
                        + (float)*(const _Float16*)(xlo + rowE * XROWB + 1024);
            float gr  = fmaf(x512f, w512r, gis[rowE * 17 + jE]        + ghs[rowE * 17 + jE]);
            float gz  = fmaf(x512f, w512z, gis[544 + rowE * 17 + jE]  + ghs[544 + rowE * 17 + jE]);
            float gni = fmaf(x512f, w512n, gis[1088 + rowE * 17 + jE]);
            float gnh = ghs[1088 + rowE * 17 + jE];
            float rg = fsig_(gr);
            float zg = fsig_(gz);
            float ng = ftanh_(fmaf(rg, gnh, gni));
            cstore1(dw + (long)(g * 32 + rowE) * RSTRIDE + jgE, (1.f - zg) * ng + zg * hp);
        }
        gbar(bar, &epoch);
    }

    // ================= k_wk_ahead head =================
    for (int kk = 0; kk < KAHEAD; ++kk) {
        {
            float v = 0.f;
            if (tid < NS) v = cload1(dw + (long)myb * RSTRIDE + tid);
            cwait();
            if (tid < NS) lh_s[tid] = v;
        }
        __syncthreads();
        {   // M1: 512 -> 256
            int n = tid & 255, q4 = tid >> 8;
            const float* av = lh_s + q4 * 128;
            const float* wp = W1 + (long)(q4 * 128) * 256 + n;
            float acc = 0.f;
            #pragma unroll 4
            for (int k2 = 0; k2 < 128; ++k2) { acc = fmaf(av[k2], wp[0], acc); wp += 256; }
            h1p[n * 4 + q4] = acc;
        }
        __syncthreads();
        if (tid < 256) {
            float v = h1p[tid * 4] + h1p[tid * 4 + 1] + h1p[tid * 4 + 2] + h1p[tid * 4 + 3];
            h1s[tid] = lrelu_(v + b1[tid]);
        }
        __syncthreads();
        if (tid < 512) {   // M2: 256 -> 128
            int n = tid & 127, q4 = tid >> 7;
            const float* av = h1s + q4 * 64;
            const float* wp = W2 + (long)(q4 * 64) * 128 + n;
            float acc = 0.f;
            #pragma unroll 4
            for (int k2 = 0; k2 < 64; ++k2) { acc = fmaf(av[k2], wp[0], acc); wp += 128; }
            h2p[n * 4 + q4] = acc;
        }
        __syncthreads();
        if (tid < 128) {
            float v = h2p[tid * 4] + h2p[tid * 4 + 1] + h2p[tid * 4 + 2] + h2p[tid * 4 + 3];
            h2s[tid] = lrelu_(v + b2[tid]);
        }
        __syncthreads();
        if (tid < 256) {   // M3: 128 -> 64
            int n = tid & 63, q4 = tid >> 6;
            const float* av = h2s + q4 * 32;
            const float* wp = W3 + (long)(q4 * 32) * 64 + n;
            float acc = 0.f;
            #pragma unroll 4
            for (int k2 = 0; k2 < 32; ++k2) { acc = fmaf(av[k2], wp[0], acc); wp += 64; }
            h3p[n * 4 + q4] = acc;
        }
        __syncthreads();
        if (tid < 64) {    // M3 epilogue + M4
            float v = h3p[tid * 4] + h3p[tid * 4 + 1] + h3p[tid * 4 + 2] + h3p[tid * 4 + 3];
            float h3v = lrelu_(v + b3[tid]);
            float p = h3v * W4[tid];
            #pragma unroll
            for (int off = 32; off >= 1; off >>= 1) p += __shfl_xor(p, off, 64);
            if (tid == 0) {
                float o = lrelu_(p + b4[0]);
                out[myb * KAHEAD + kk] = o;
                cstore1(xw + (long)myb * RSTRIDE + XSLOT, o);
            }
        }
        if (kk < KAHEAD - 1) {
            gbar(bar, &epoch);
            float hp = 0.f;
            if (tid < 512) hp = cload1(dw + (long)(g * 32 + rowE) * RSTRIDE + jgE);
            stagePanel(gPanelD, xhi, xlo, tid);
            __syncthreads();
            DO_GEMMA(false);
            __syncthreads();
            stagePanel(gPanelX, xhi, xlo, tid);
            __syncthreads();
            DO_GEMMC();
            __syncthreads();
            if (tid < 512) {
                float x512f = (float)*(const _Float16*)(xhi + rowE * XROWB + 1024)
                            + (float)*(const _Float16*)(xlo + rowE * XROWB + 1024);
                float gr  = fmaf(x512f, w512r, gis[rowE * 17 + jE]        + ghs[rowE * 17 + jE]);
                float gz  = fmaf(x512f, w512z, gis[544 + rowE * 17 + jE]  + ghs[544 + rowE * 17 + jE]);
                float gni = fmaf(x512f, w512n, gis[1088 + rowE * 17 + jE]);
                float gnh = ghs[1088 + rowE * 17 + jE];
                float rg = fsig_(gr);
                float zg = fsig_(gz);
                float ng = ftanh_(fmaf(rg, gnh, gni));
                cstore1(dw + (long)(g * 32 + rowE) * RSTRIDE + jgE, (1.f - zg) * ng + zg * hp);
            }
            gbar(bar, &epoch);
        }
    }
}

// ---------------- host ----------------
extern "C" void kernel_launch(void* const* d_in, const int* in_sizes, int n_in,
                              void* d_out, int out_size, void* d_ws, size_t ws_size,
                              hipStream_t stream) {
    const float* hiddens = (const float*)d_in[0];
    const float* allys   = (const float*)d_in[1];
    const float* Wh   = (const float*)d_in[3];
    const float* bh   = (const float*)d_in[4];
    const float* Ws   = (const float*)d_in[5];
    const float* bs   = (const float*)d_in[6];
    const float* Wo   = (const float*)d_in[7];
    const float* bo   = (const float*)d_in[8];
    const float* W_ih = (const float*)d_in[9];
    const float* W_hh = (const float*)d_in[10];
    const float* b_ih = (const float*)d_in[11];
    const float* b_hh = (const float*)d_in[12];
    const float* W1 = (const float*)d_in[13];
    const float* b1 = (const float*)d_in[14];
    const float* W2 = (const float*)d_in[15];
    const float* b2 = (const float*)d_in[16];
    const float* W3 = (const float*)d_in[17];
    const float* b3 = (const float*)d_in[18];
    const float* W4 = (const float*)d_in[19];
    const float* b4 = (const float*)d_in[20];
    float* wsf = (float*)d_ws;
    float* outf = (float*)d_out;

    if (ws_size < (size_t)WS_FLOATS * sizeof(float)) {
        fprintf(stderr, "kernel_launch: workspace too small (%zu < %zu)\n",
                ws_size, (size_t)WS_FLOATS * sizeof(float));
        return;
    }

    prep_kernel<<<dim3(2048), dim3(256), 0, stream>>>(W_hh, W_ih, Wh, Ws, wsf);

    (void)hipFuncSetAttribute((const void*)fused_kernel,
                              hipFuncAttributeMaxDynamicSharedMemorySize, LDS_BYTES);

    void* args[] = { &hiddens, &allys, &bs, &Wo, &bo, &bh,
                     &b_ih, &b_hh, &W_ih, &W1, &b1, &W2, &b2, &W3, &b3, &W4, &b4,
                     &wsf, &outf };
    hipError_t e = hipLaunchCooperativeKernel((void*)fused_kernel,
                                              dim3(NBLOCKS), dim3(NTHREADS),
                                              args, LDS_BYTES, stream);
    if (e != hipSuccess) {
        fprintf(stderr, "coop launch failed (%d); plain fallback\n", (int)e);
        (void)hipGetLastError();
        fused_kernel<<<dim3(NBLOCKS), dim3(NTHREADS), LDS_BYTES, stream>>>(
            hiddens, allys, bs, Wo, bo, bh, b_ih, b_hh, W_ih,
            W1, b1, W2, b2, W3, b3, W4, b4, wsf, outf);
    }
}